// Round 6
// baseline (901.707 us; speedup 1.0000x reference)
//
#include <hip/hip_runtime.h>
#include <hip/hip_bf16.h>

typedef __attribute__((ext_vector_type(8))) __bf16 bf16x8;
typedef __attribute__((ext_vector_type(4))) float floatx4;

#define S_LEN 4096
#define NBH   64
#define BM    256   // q rows per block (8 waves x 32)
#define BN    64    // keys per compute subtile
#define PH    128   // keys per staging phase (2 subtiles, double-buffered)
#define KSTR  72    // padded K row stride (shorts)
#define VSTR  136   // padded V^T row stride (shorts, 128 keys + 8 pad)
#define C_SCALE 0.18033688011112042f  // log2(e) / sqrt(64)

__device__ __forceinline__ short f2bf(float x) {
  __hip_bfloat16 h = __float2bfloat16(x);
  return *reinterpret_cast<const short*>(&h);
}

// Round-5 verified compute core (key-permuted P->PV in-register repack) +
// this round: double-buffered 128-key staging phases, ONE barrier per phase
// (4x fewer barriers). 2-buffer rotation makes the single barrier sufficient:
// buf[cur] written in ph is re-written in ph+2, with ph+1's barrier between
// the last read (ph's compute) and that rewrite.
__global__ __launch_bounds__(512, 4)
void mea_fwd(const float* __restrict__ qp, const float* __restrict__ kp,
             const float* __restrict__ vp, const int* __restrict__ cm,
             float* __restrict__ op)
{
  __shared__ short kL[2][PH * KSTR];    // K tile  [key 0..127][d]    (bf16)
  __shared__ short vT[2][64 * VSTR];    // V^T     [d][pvslot 0..127] (bf16, per-64 key perm + d-rotation)

  const int t    = threadIdx.x;
  const int w    = t >> 6;
  const int lane = t & 63;
  const int lg   = lane >> 4;
  const int l16  = lane & 15;

  const int bh  = blockIdx.y;
  const int qt  = (int)(gridDim.x - 1) - (int)blockIdx.x;  // big blocks first
  const int q0  = qt * BM;
  const int qw0 = q0 + w * 32;            // this wave's first q row
  const long base = (long)bh * S_LEN * 64;
  const int causal = cm[0];

  // staging: 512 threads x 2 key-rows (skr, skr+64) x 8 d-elems
  const int skr = t >> 3;                 // key row within 64-subtile (0..63)
  const int sd0 = (t & 7) * 8;            // first d (0,8,...,56)
  // pvslot = bit-permuted key slot within subtile: p(s)=32*s4+16*s3+8*s2+4*s5+(s&3)
  const int pcol = ((skr >> 4) & 1) * 32 + ((skr >> 3) & 1) * 16 +
                   ((skr >> 2) & 1) * 8  + ((skr >> 5) & 1) * 4 + (skr & 3);
  const int svcol = (pcol + (sd0 >> 4) * 16) & 63;  // + d-dependent bank rotation

  // Q as B-fragments with softmax scale folded in
  bf16x8 qfrag[2][2];
#pragma unroll
  for (int nt = 0; nt < 2; ++nt)
#pragma unroll
    for (int ks = 0; ks < 2; ++ks) {
      const float* qr = qp + base + (long)(qw0 + nt*16 + l16) * 64 + ks*32 + lg*8;
      float4 a = *(const float4*)(qr);
      float4 b = *(const float4*)(qr + 4);
      union { short s[8]; bf16x8 v; } u;
      u.s[0]=f2bf(a.x*C_SCALE); u.s[1]=f2bf(a.y*C_SCALE);
      u.s[2]=f2bf(a.z*C_SCALE); u.s[3]=f2bf(a.w*C_SCALE);
      u.s[4]=f2bf(b.x*C_SCALE); u.s[5]=f2bf(b.y*C_SCALE);
      u.s[6]=f2bf(b.z*C_SCALE); u.s[7]=f2bf(b.w*C_SCALE);
      qfrag[nt][ks] = u.v;
    }

  floatx4 oacc[2][4];
#pragma unroll
  for (int i = 0; i < 2; ++i)
#pragma unroll
    for (int j = 0; j < 4; ++j)
      oacc[i][j] = (floatx4){0.f, 0.f, 0.f, 0.f};

  float m_run[2] = {-__builtin_inff(), -__builtin_inff()};
  float l_run[2] = {0.f, 0.f};

  const int kmax = causal ? (q0 + BM) : S_LEN;   // divisible by 256
  const int nph  = kmax / PH;

  // ---- prefetch phase 0 into registers ----
  float4 kpre[2][2], vpre[2][2];
  {
    const float* kb = kp + base + (long)skr * 64 + sd0;
    kpre[0][0] = ((const float4*)kb)[0];        kpre[0][1] = ((const float4*)kb)[1];
    kpre[1][0] = ((const float4*)(kb + 4096))[0]; kpre[1][1] = ((const float4*)(kb + 4096))[1]; // +64 rows
    const float* vb = vp + base + (long)skr * 64 + sd0;
    vpre[0][0] = ((const float4*)vb)[0];        vpre[0][1] = ((const float4*)vb)[1];
    vpre[1][0] = ((const float4*)(vb + 4096))[0]; vpre[1][1] = ((const float4*)(vb + 4096))[1];
  }

  int cur = 0;
  for (int ph = 0; ph < nph; ++ph) {

    // ---- store prefetched regs -> LDS buf[cur] (cvt f32->bf16) ----
#pragma unroll
    for (int h = 0; h < 2; ++h) {
      union { short s[8]; uint4 u; } pk;
      pk.s[0]=f2bf(kpre[h][0].x); pk.s[1]=f2bf(kpre[h][0].y);
      pk.s[2]=f2bf(kpre[h][0].z); pk.s[3]=f2bf(kpre[h][0].w);
      pk.s[4]=f2bf(kpre[h][1].x); pk.s[5]=f2bf(kpre[h][1].y);
      pk.s[6]=f2bf(kpre[h][1].z); pk.s[7]=f2bf(kpre[h][1].w);
      *(uint4*)(&kL[cur][(h*64 + skr) * KSTR + sd0]) = pk.u;

      short vs[8];
      vs[0]=f2bf(vpre[h][0].x); vs[1]=f2bf(vpre[h][0].y);
      vs[2]=f2bf(vpre[h][0].z); vs[3]=f2bf(vpre[h][0].w);
      vs[4]=f2bf(vpre[h][1].x); vs[5]=f2bf(vpre[h][1].y);
      vs[6]=f2bf(vpre[h][1].z); vs[7]=f2bf(vpre[h][1].w);
#pragma unroll
      for (int i = 0; i < 8; ++i)
        vT[cur][(sd0 + i) * VSTR + h*64 + svcol] = vs[i];
    }
    __syncthreads();   // single barrier per phase

    // ---- issue next phase's global loads (consumed at top of next phase) ----
    if (ph + 1 < nph) {
      const int kn = (ph + 1) * PH;
      const float* kb = kp + base + (long)(kn + skr) * 64 + sd0;
      kpre[0][0] = ((const float4*)kb)[0];        kpre[0][1] = ((const float4*)kb)[1];
      kpre[1][0] = ((const float4*)(kb + 4096))[0]; kpre[1][1] = ((const float4*)(kb + 4096))[1];
      const float* vb = vp + base + (long)(kn + skr) * 64 + sd0;
      vpre[0][0] = ((const float4*)vb)[0];        vpre[0][1] = ((const float4*)vb)[1];
      vpre[1][0] = ((const float4*)(vb + 4096))[0]; vpre[1][1] = ((const float4*)(vb + 4096))[1];
    }

    const short* kb_ = kL[cur];
    const short* vb_ = vT[cur];

#pragma unroll
    for (int sub = 0; sub < 2; ++sub) {
      const int k0 = ph * PH + sub * 64;
      if (causal && k0 >= qw0 + 32) continue;   // subtile fully masked for this wave

      // ---- S^T = K * Q^T : C[row=key][col=q], log2 domain ----
      floatx4 sacc[4][2];
#pragma unroll
      for (int mt = 0; mt < 4; ++mt)
#pragma unroll
        for (int nt = 0; nt < 2; ++nt)
          sacc[mt][nt] = (floatx4){0.f, 0.f, 0.f, 0.f};
#pragma unroll
      for (int ks = 0; ks < 2; ++ks)
#pragma unroll
        for (int mt = 0; mt < 4; ++mt) {
          bf16x8 kfrag = *(const bf16x8*)(&kb_[(sub*64 + mt*16 + l16) * KSTR + ks*32 + lg*8]);
#pragma unroll
          for (int nt = 0; nt < 2; ++nt)
            sacc[mt][nt] = __builtin_amdgcn_mfma_f32_16x16x32_bf16(kfrag, qfrag[nt][ks], sacc[mt][nt], 0, 0, 0);
        }

      // ---- online softmax (exp2 domain) ----
      const bool needmask = causal && (k0 + BN - 1 > qw0);
      float mnew[2] = {m_run[0], m_run[1]};
#pragma unroll
      for (int mt = 0; mt < 4; ++mt)
#pragma unroll
        for (int nt = 0; nt < 2; ++nt)
#pragma unroll
          for (int r = 0; r < 4; ++r) {
            float v = sacc[mt][nt][r];
            if (needmask) {
              int key = k0  + mt*16 + lg*4 + r;
              int q   = qw0 + nt*16 + l16;
              if (q < key) v = -__builtin_inff();
            }
            sacc[mt][nt][r] = v;
            mnew[nt] = fmaxf(mnew[nt], v);
          }
#pragma unroll
      for (int nt = 0; nt < 2; ++nt) {
        mnew[nt] = fmaxf(mnew[nt], __shfl_xor(mnew[nt], 16));
        mnew[nt] = fmaxf(mnew[nt], __shfl_xor(mnew[nt], 32));
      }
      float alpha[2], rsum[2];
#pragma unroll
      for (int nt = 0; nt < 2; ++nt) {
        alpha[nt] = __builtin_amdgcn_exp2f(m_run[nt] - mnew[nt]);  // first tile: exp2(-inf)=0
        m_run[nt] = mnew[nt];
        rsum[nt]  = 0.f;
      }
      // exp + pack P directly into PV A-fragments (key perm: j=0..3 <- mt=ks, j=4..7 <- mt=ks+2)
      bf16x8 pfrag[2][2];
#pragma unroll
      for (int nt = 0; nt < 2; ++nt)
#pragma unroll
        for (int ks = 0; ks < 2; ++ks) {
          union { short s[8]; bf16x8 v; } pk;
#pragma unroll
          for (int r = 0; r < 4; ++r) {
            float e0 = __builtin_amdgcn_exp2f(sacc[ks][nt][r]     - mnew[nt]);
            float e1 = __builtin_amdgcn_exp2f(sacc[ks + 2][nt][r] - mnew[nt]);
            rsum[nt] += e0 + e1;
            pk.s[r]     = f2bf(e0);
            pk.s[4 + r] = f2bf(e1);
          }
          pfrag[nt][ks] = pk.v;
        }
#pragma unroll
      for (int nt = 0; nt < 2; ++nt) {
        rsum[nt] += __shfl_xor(rsum[nt], 16);
        rsum[nt] += __shfl_xor(rsum[nt], 32);
        l_run[nt] = l_run[nt] * alpha[nt] + rsum[nt];
      }
      // rescale O accumulator (alpha from q=l16 layout to q=lg*4+r layout)
#pragma unroll
      for (int mo = 0; mo < 2; ++mo)
#pragma unroll
        for (int r = 0; r < 4; ++r) {
          float al = __shfl(alpha[mo], lg*4 + r);
#pragma unroll
          for (int nd = 0; nd < 4; ++nd)
            oacc[mo][nd][r] *= al;
        }

      // ---- O += P * V (V^T columns key-permuted to match pfrag) ----
#pragma unroll
      for (int ks = 0; ks < 2; ++ks) {
        bf16x8 vfrag[4];
#pragma unroll
        for (int nd = 0; nd < 4; ++nd) {
          int colr = (ks*32 + lg*8 + nd*16) & 63;   // un-rotate d-dependent rotation
          vfrag[nd] = *(const bf16x8*)(&vb_[(nd*16 + l16) * VSTR + sub*64 + colr]);
        }
#pragma unroll
        for (int mo = 0; mo < 2; ++mo)
#pragma unroll
          for (int nd = 0; nd < 4; ++nd)
            oacc[mo][nd] = __builtin_amdgcn_mfma_f32_16x16x32_bf16(pfrag[mo][ks], vfrag[nd], oacc[mo][nd], 0, 0, 0);
      }
    }

    cur ^= 1;   // no second barrier: ph+1's barrier guards buf reuse at ph+2
  }

  // ---- epilogue: O / l, f32 out ----
#pragma unroll
  for (int mo = 0; mo < 2; ++mo)
#pragma unroll
    for (int r = 0; r < 4; ++r) {
      float lv  = __shfl(l_run[mo], lg*4 + r);
      float inv = __builtin_amdgcn_rcpf(lv);
      int qrow  = qw0 + mo*16 + lg*4 + r;
#pragma unroll
      for (int nd = 0; nd < 4; ++nd)
        op[base + (long)qrow * 64 + nd*16 + l16] = oacc[mo][nd][r] * inv;
    }
}

extern "C" void kernel_launch(void* const* d_in, const int* in_sizes, int n_in,
                              void* d_out, int out_size, void* d_ws, size_t ws_size,
                              hipStream_t stream) {
  const float* q = (const float*)d_in[0];
  const float* k = (const float*)d_in[1];
  const float* v = (const float*)d_in[2];
  const int*  cm = (const int*)d_in[3];
  float* o = (float*)d_out;
  dim3 grid(S_LEN / BM, NBH);
  mea_fwd<<<grid, dim3(512, 1, 1), 0, stream>>>(q, k, v, cm, o);
}

// Round 7
// 654.980 us; speedup vs baseline: 1.3767x; 1.3767x over previous
//
#include <hip/hip_runtime.h>
#include <hip/hip_bf16.h>

typedef __attribute__((ext_vector_type(8))) __bf16 bf16x8;
typedef __attribute__((ext_vector_type(4))) float floatx4;

#define S_LEN 4096
#define NBH   64
#define BM    256   // q rows per block (8 waves x 32)
#define BN    64    // keys per compute subtile
#define PH    128   // keys per staging phase (2 subtiles, double-buffered)
#define KSTR  72    // padded K row stride (shorts)
#define VSTR  136   // padded V^T row stride (shorts, 128 keys + 8 pad)
#define C_SCALE 0.18033688011112042f  // log2(e) / sqrt(64)

__device__ __forceinline__ short f2bf(float x) {
  __hip_bfloat16 h = __float2bfloat16(x);
  return *reinterpret_cast<const short*>(&h);
}

// Round-5 verified compute core (key-permuted P->PV in-register repack) +
// double-buffered 128-key staging phases, ONE barrier per phase (4x fewer
// than round 5). NOTE: no min-waves launch_bounds clamp — round 6 proved
// (WRITE_SIZE 65->713 MB) that forcing the 64-VGPR bin spills the ~104-reg
// live state to scratch. Irreducible per-wave state (oacc 32 + qfrag 16 +
// prefetch 32 + softmax state) targets the <=128 VGPR bin; 4 waves/SIMD.
__global__ __launch_bounds__(512)
void mea_fwd(const float* __restrict__ qp, const float* __restrict__ kp,
             const float* __restrict__ vp, const int* __restrict__ cm,
             float* __restrict__ op)
{
  __shared__ short kL[2][PH * KSTR];    // K tile  [key 0..127][d]    (bf16)
  __shared__ short vT[2][64 * VSTR];    // V^T     [d][pvslot 0..127] (bf16, per-64 key perm + d-rotation)

  const int t    = threadIdx.x;
  const int w    = t >> 6;
  const int lane = t & 63;
  const int lg   = lane >> 4;
  const int l16  = lane & 15;

  const int bh  = blockIdx.y;
  const int qt  = (int)(gridDim.x - 1) - (int)blockIdx.x;  // big blocks first
  const int q0  = qt * BM;
  const int qw0 = q0 + w * 32;            // this wave's first q row
  const long base = (long)bh * S_LEN * 64;
  const int causal = cm[0];

  // staging: 512 threads x 2 key-rows (skr, skr+64) x 8 d-elems
  const int skr = t >> 3;                 // key row within 64-subtile (0..63)
  const int sd0 = (t & 7) * 8;            // first d (0,8,...,56)
  // pvslot = bit-permuted key slot within subtile: p(s)=32*s4+16*s3+8*s2+4*s5+(s&3)
  const int pcol = ((skr >> 4) & 1) * 32 + ((skr >> 3) & 1) * 16 +
                   ((skr >> 2) & 1) * 8  + ((skr >> 5) & 1) * 4 + (skr & 3);
  const int svcol = (pcol + (sd0 >> 4) * 16) & 63;  // + d-dependent bank rotation

  // Q as B-fragments with softmax scale folded in
  bf16x8 qfrag[2][2];
#pragma unroll
  for (int nt = 0; nt < 2; ++nt)
#pragma unroll
    for (int ks = 0; ks < 2; ++ks) {
      const float* qr = qp + base + (long)(qw0 + nt*16 + l16) * 64 + ks*32 + lg*8;
      float4 a = *(const float4*)(qr);
      float4 b = *(const float4*)(qr + 4);
      union { short s[8]; bf16x8 v; } u;
      u.s[0]=f2bf(a.x*C_SCALE); u.s[1]=f2bf(a.y*C_SCALE);
      u.s[2]=f2bf(a.z*C_SCALE); u.s[3]=f2bf(a.w*C_SCALE);
      u.s[4]=f2bf(b.x*C_SCALE); u.s[5]=f2bf(b.y*C_SCALE);
      u.s[6]=f2bf(b.z*C_SCALE); u.s[7]=f2bf(b.w*C_SCALE);
      qfrag[nt][ks] = u.v;
    }

  floatx4 oacc[2][4];
#pragma unroll
  for (int i = 0; i < 2; ++i)
#pragma unroll
    for (int j = 0; j < 4; ++j)
      oacc[i][j] = (floatx4){0.f, 0.f, 0.f, 0.f};

  float m_run[2] = {-__builtin_inff(), -__builtin_inff()};
  float l_run[2] = {0.f, 0.f};

  const int kmax = causal ? (q0 + BM) : S_LEN;   // divisible by 256
  const int nph  = kmax / PH;

  // ---- prefetch phase 0 into registers ----
  float4 kpre[2][2], vpre[2][2];
  {
    const float* kb = kp + base + (long)skr * 64 + sd0;
    kpre[0][0] = ((const float4*)kb)[0];          kpre[0][1] = ((const float4*)kb)[1];
    kpre[1][0] = ((const float4*)(kb + 4096))[0]; kpre[1][1] = ((const float4*)(kb + 4096))[1]; // +64 rows
    const float* vb = vp + base + (long)skr * 64 + sd0;
    vpre[0][0] = ((const float4*)vb)[0];          vpre[0][1] = ((const float4*)vb)[1];
    vpre[1][0] = ((const float4*)(vb + 4096))[0]; vpre[1][1] = ((const float4*)(vb + 4096))[1];
  }

  int cur = 0;
  for (int ph = 0; ph < nph; ++ph) {

    // ---- store prefetched regs -> LDS buf[cur] (cvt f32->bf16) ----
#pragma unroll
    for (int h = 0; h < 2; ++h) {
      union { short s[8]; uint4 u; } pk;
      pk.s[0]=f2bf(kpre[h][0].x); pk.s[1]=f2bf(kpre[h][0].y);
      pk.s[2]=f2bf(kpre[h][0].z); pk.s[3]=f2bf(kpre[h][0].w);
      pk.s[4]=f2bf(kpre[h][1].x); pk.s[5]=f2bf(kpre[h][1].y);
      pk.s[6]=f2bf(kpre[h][1].z); pk.s[7]=f2bf(kpre[h][1].w);
      *(uint4*)(&kL[cur][(h*64 + skr) * KSTR + sd0]) = pk.u;

      short vs[8];
      vs[0]=f2bf(vpre[h][0].x); vs[1]=f2bf(vpre[h][0].y);
      vs[2]=f2bf(vpre[h][0].z); vs[3]=f2bf(vpre[h][0].w);
      vs[4]=f2bf(vpre[h][1].x); vs[5]=f2bf(vpre[h][1].y);
      vs[6]=f2bf(vpre[h][1].z); vs[7]=f2bf(vpre[h][1].w);
#pragma unroll
      for (int i = 0; i < 8; ++i)
        vT[cur][(sd0 + i) * VSTR + h*64 + svcol] = vs[i];
    }
    __syncthreads();   // single barrier per phase

    // ---- issue next phase's global loads (consumed at top of next phase) ----
    if (ph + 1 < nph) {
      const int kn = (ph + 1) * PH;
      const float* kb = kp + base + (long)(kn + skr) * 64 + sd0;
      kpre[0][0] = ((const float4*)kb)[0];          kpre[0][1] = ((const float4*)kb)[1];
      kpre[1][0] = ((const float4*)(kb + 4096))[0]; kpre[1][1] = ((const float4*)(kb + 4096))[1];
      const float* vb = vp + base + (long)(kn + skr) * 64 + sd0;
      vpre[0][0] = ((const float4*)vb)[0];          vpre[0][1] = ((const float4*)vb)[1];
      vpre[1][0] = ((const float4*)(vb + 4096))[0]; vpre[1][1] = ((const float4*)(vb + 4096))[1];
    }

    const short* kb_ = kL[cur];
    const short* vb_ = vT[cur];

#pragma unroll
    for (int sub = 0; sub < 2; ++sub) {
      const int k0 = ph * PH + sub * 64;
      if (causal && k0 >= qw0 + 32) continue;   // subtile fully masked for this wave

      // ---- S^T = K * Q^T : C[row=key][col=q], log2 domain ----
      floatx4 sacc[4][2];
#pragma unroll
      for (int mt = 0; mt < 4; ++mt)
#pragma unroll
        for (int nt = 0; nt < 2; ++nt)
          sacc[mt][nt] = (floatx4){0.f, 0.f, 0.f, 0.f};
#pragma unroll
      for (int ks = 0; ks < 2; ++ks)
#pragma unroll
        for (int mt = 0; mt < 4; ++mt) {
          bf16x8 kfrag = *(const bf16x8*)(&kb_[(sub*64 + mt*16 + l16) * KSTR + ks*32 + lg*8]);
#pragma unroll
          for (int nt = 0; nt < 2; ++nt)
            sacc[mt][nt] = __builtin_amdgcn_mfma_f32_16x16x32_bf16(kfrag, qfrag[nt][ks], sacc[mt][nt], 0, 0, 0);
        }

      // ---- online softmax (exp2 domain) ----
      const bool needmask = causal && (k0 + BN - 1 > qw0);
      float mnew[2] = {m_run[0], m_run[1]};
#pragma unroll
      for (int mt = 0; mt < 4; ++mt)
#pragma unroll
        for (int nt = 0; nt < 2; ++nt)
#pragma unroll
          for (int r = 0; r < 4; ++r) {
            float v = sacc[mt][nt][r];
            if (needmask) {
              int key = k0  + mt*16 + lg*4 + r;
              int q   = qw0 + nt*16 + l16;
              if (q < key) v = -__builtin_inff();
            }
            sacc[mt][nt][r] = v;
            mnew[nt] = fmaxf(mnew[nt], v);
          }
#pragma unroll
      for (int nt = 0; nt < 2; ++nt) {
        mnew[nt] = fmaxf(mnew[nt], __shfl_xor(mnew[nt], 16));
        mnew[nt] = fmaxf(mnew[nt], __shfl_xor(mnew[nt], 32));
      }
      float alpha[2], rsum[2];
#pragma unroll
      for (int nt = 0; nt < 2; ++nt) {
        alpha[nt] = __builtin_amdgcn_exp2f(m_run[nt] - mnew[nt]);  // first tile: exp2(-inf)=0
        m_run[nt] = mnew[nt];
        rsum[nt]  = 0.f;
      }
      // exp + pack P directly into PV A-fragments (key perm: j=0..3 <- mt=ks, j=4..7 <- mt=ks+2)
      bf16x8 pfrag[2][2];
#pragma unroll
      for (int nt = 0; nt < 2; ++nt)
#pragma unroll
        for (int ks = 0; ks < 2; ++ks) {
          union { short s[8]; bf16x8 v; } pk;
#pragma unroll
          for (int r = 0; r < 4; ++r) {
            float e0 = __builtin_amdgcn_exp2f(sacc[ks][nt][r]     - mnew[nt]);
            float e1 = __builtin_amdgcn_exp2f(sacc[ks + 2][nt][r] - mnew[nt]);
            rsum[nt] += e0 + e1;
            pk.s[r]     = f2bf(e0);
            pk.s[4 + r] = f2bf(e1);
          }
          pfrag[nt][ks] = pk.v;
        }
#pragma unroll
      for (int nt = 0; nt < 2; ++nt) {
        rsum[nt] += __shfl_xor(rsum[nt], 16);
        rsum[nt] += __shfl_xor(rsum[nt], 32);
        l_run[nt] = l_run[nt] * alpha[nt] + rsum[nt];
      }
      // rescale O accumulator (alpha from q=l16 layout to q=lg*4+r layout)
#pragma unroll
      for (int mo = 0; mo < 2; ++mo)
#pragma unroll
        for (int r = 0; r < 4; ++r) {
          float al = __shfl(alpha[mo], lg*4 + r);
#pragma unroll
          for (int nd = 0; nd < 4; ++nd)
            oacc[mo][nd][r] *= al;
        }

      // ---- O += P * V (V^T columns key-permuted to match pfrag) ----
#pragma unroll
      for (int ks = 0; ks < 2; ++ks) {
        bf16x8 vfrag[4];
#pragma unroll
        for (int nd = 0; nd < 4; ++nd) {
          int colr = (ks*32 + lg*8 + nd*16) & 63;   // un-rotate d-dependent rotation
          vfrag[nd] = *(const bf16x8*)(&vb_[(nd*16 + l16) * VSTR + sub*64 + colr]);
        }
#pragma unroll
        for (int mo = 0; mo < 2; ++mo)
#pragma unroll
          for (int nd = 0; nd < 4; ++nd)
            oacc[mo][nd] = __builtin_amdgcn_mfma_f32_16x16x32_bf16(pfrag[mo][ks], vfrag[nd], oacc[mo][nd], 0, 0, 0);
      }
    }

    cur ^= 1;   // no second barrier: ph+1's barrier guards buf reuse at ph+2
  }

  // ---- epilogue: O / l, f32 out ----
#pragma unroll
  for (int mo = 0; mo < 2; ++mo)
#pragma unroll
    for (int r = 0; r < 4; ++r) {
      float lv  = __shfl(l_run[mo], lg*4 + r);
      float inv = __builtin_amdgcn_rcpf(lv);
      int qrow  = qw0 + mo*16 + lg*4 + r;
#pragma unroll
      for (int nd = 0; nd < 4; ++nd)
        op[base + (long)qrow * 64 + nd*16 + l16] = oacc[mo][nd][r] * inv;
    }
}

extern "C" void kernel_launch(void* const* d_in, const int* in_sizes, int n_in,
                              void* d_out, int out_size, void* d_ws, size_t ws_size,
                              hipStream_t stream) {
  const float* q = (const float*)d_in[0];
  const float* k = (const float*)d_in[1];
  const float* v = (const float*)d_in[2];
  const int*  cm = (const int*)d_in[3];
  float* o = (float*)d_out;
  dim3 grid(S_LEN / BM, NBH);
  mea_fwd<<<grid, dim3(512, 1, 1), 0, stream>>>(q, k, v, cm, o);
}

// Round 8
// 574.917 us; speedup vs baseline: 1.5684x; 1.1393x over previous
//
#include <hip/hip_runtime.h>
#include <hip/hip_bf16.h>

typedef __attribute__((ext_vector_type(8))) __bf16 bf16x8;
typedef __attribute__((ext_vector_type(4))) float floatx4;

#define S_LEN 4096
#define NBH   64
#define BM    256   // q rows per block (8 waves x 32)
#define BN    64    // keys per compute subtile
#define PH    128   // keys per staging phase (2 subtiles, double-buffered)
#define KSTR  72    // padded K row stride (shorts)
#define VSTR  136   // padded V^T row stride (shorts, 128 keys + 8 pad)
#define C_SCALE 0.18033688011112042f  // log2(e) / sqrt(64)
#define RESCALE_THR 8.0f              // defer-max threshold (log2 domain)

__device__ __forceinline__ short f2bf(float x) {
  __hip_bfloat16 h = __float2bfloat16(x);
  return *reinterpret_cast<const short*>(&h);
}

// Round-7 structure (dbuf 128-key phases, 1 barrier/phase, key-permuted
// in-register P->PV) + this round: DEFER-MAX online softmax.
//   - One __all ballot per subtile; if max growth <= THR (log2 domain), skip
//     the max reduce (4 bpermute), alpha broadcast (8 bpermute), O/l rescale
//     (32 mul + 2 exp2). P = exp2(s - m_old), bounded by 2^8 — bf16/f32 safe.
//   - l_run kept as per-lane PARTIAL sums (lg copies hold disjoint key sets),
//     reduced once in the epilogue — removes the per-subtile rsum reduce
//     (4 bpermute) from the common path too.
// Steady-state subtile: ZERO cross-lane ops (was 16 ds_bpermute, serial).
__global__ __launch_bounds__(512)
void mea_fwd(const float* __restrict__ qp, const float* __restrict__ kp,
             const float* __restrict__ vp, const int* __restrict__ cm,
             float* __restrict__ op)
{
  __shared__ short kL[2][PH * KSTR];    // K tile  [key 0..127][d]    (bf16)
  __shared__ short vT[2][64 * VSTR];    // V^T     [d][pvslot 0..127] (bf16, per-64 key perm + d-rotation)

  const int t    = threadIdx.x;
  const int w    = t >> 6;
  const int lane = t & 63;
  const int lg   = lane >> 4;
  const int l16  = lane & 15;

  const int bh  = blockIdx.y;
  const int qt  = (int)(gridDim.x - 1) - (int)blockIdx.x;  // big blocks first
  const int q0  = qt * BM;
  const int qw0 = q0 + w * 32;            // this wave's first q row
  const long base = (long)bh * S_LEN * 64;
  const int causal = cm[0];

  // staging: 512 threads x 2 key-rows (skr, skr+64) x 8 d-elems
  const int skr = t >> 3;                 // key row within 64-subtile (0..63)
  const int sd0 = (t & 7) * 8;            // first d (0,8,...,56)
  // pvslot = bit-permuted key slot within subtile: p(s)=32*s4+16*s3+8*s2+4*s5+(s&3)
  const int pcol = ((skr >> 4) & 1) * 32 + ((skr >> 3) & 1) * 16 +
                   ((skr >> 2) & 1) * 8  + ((skr >> 5) & 1) * 4 + (skr & 3);
  const int svcol = (pcol + (sd0 >> 4) * 16) & 63;  // + d-dependent bank rotation

  // Q as B-fragments with softmax scale folded in
  bf16x8 qfrag[2][2];
#pragma unroll
  for (int nt = 0; nt < 2; ++nt)
#pragma unroll
    for (int ks = 0; ks < 2; ++ks) {
      const float* qr = qp + base + (long)(qw0 + nt*16 + l16) * 64 + ks*32 + lg*8;
      float4 a = *(const float4*)(qr);
      float4 b = *(const float4*)(qr + 4);
      union { short s[8]; bf16x8 v; } u;
      u.s[0]=f2bf(a.x*C_SCALE); u.s[1]=f2bf(a.y*C_SCALE);
      u.s[2]=f2bf(a.z*C_SCALE); u.s[3]=f2bf(a.w*C_SCALE);
      u.s[4]=f2bf(b.x*C_SCALE); u.s[5]=f2bf(b.y*C_SCALE);
      u.s[6]=f2bf(b.z*C_SCALE); u.s[7]=f2bf(b.w*C_SCALE);
      qfrag[nt][ks] = u.v;
    }

  floatx4 oacc[2][4];
#pragma unroll
  for (int i = 0; i < 2; ++i)
#pragma unroll
    for (int j = 0; j < 4; ++j)
      oacc[i][j] = (floatx4){0.f, 0.f, 0.f, 0.f};

  float m_run[2] = {-__builtin_inff(), -__builtin_inff()};
  float l_run[2] = {0.f, 0.f};   // per-lane PARTIAL sums (reduced in epilogue)

  const int kmax = causal ? (q0 + BM) : S_LEN;   // divisible by 256
  const int nph  = kmax / PH;

  // ---- prefetch phase 0 into registers ----
  float4 kpre[2][2], vpre[2][2];
  {
    const float* kb = kp + base + (long)skr * 64 + sd0;
    kpre[0][0] = ((const float4*)kb)[0];          kpre[0][1] = ((const float4*)kb)[1];
    kpre[1][0] = ((const float4*)(kb + 4096))[0]; kpre[1][1] = ((const float4*)(kb + 4096))[1]; // +64 rows
    const float* vb = vp + base + (long)skr * 64 + sd0;
    vpre[0][0] = ((const float4*)vb)[0];          vpre[0][1] = ((const float4*)vb)[1];
    vpre[1][0] = ((const float4*)(vb + 4096))[0]; vpre[1][1] = ((const float4*)(vb + 4096))[1];
  }

  int cur = 0;
  for (int ph = 0; ph < nph; ++ph) {

    // ---- store prefetched regs -> LDS buf[cur] (cvt f32->bf16) ----
#pragma unroll
    for (int h = 0; h < 2; ++h) {
      union { short s[8]; uint4 u; } pk;
      pk.s[0]=f2bf(kpre[h][0].x); pk.s[1]=f2bf(kpre[h][0].y);
      pk.s[2]=f2bf(kpre[h][0].z); pk.s[3]=f2bf(kpre[h][0].w);
      pk.s[4]=f2bf(kpre[h][1].x); pk.s[5]=f2bf(kpre[h][1].y);
      pk.s[6]=f2bf(kpre[h][1].z); pk.s[7]=f2bf(kpre[h][1].w);
      *(uint4*)(&kL[cur][(h*64 + skr) * KSTR + sd0]) = pk.u;

      short vs[8];
      vs[0]=f2bf(vpre[h][0].x); vs[1]=f2bf(vpre[h][0].y);
      vs[2]=f2bf(vpre[h][0].z); vs[3]=f2bf(vpre[h][0].w);
      vs[4]=f2bf(vpre[h][1].x); vs[5]=f2bf(vpre[h][1].y);
      vs[6]=f2bf(vpre[h][1].z); vs[7]=f2bf(vpre[h][1].w);
#pragma unroll
      for (int i = 0; i < 8; ++i)
        vT[cur][(sd0 + i) * VSTR + h*64 + svcol] = vs[i];
    }
    __syncthreads();   // single barrier per phase

    // ---- issue next phase's global loads (consumed at top of next phase) ----
    if (ph + 1 < nph) {
      const int kn = (ph + 1) * PH;
      const float* kb = kp + base + (long)(kn + skr) * 64 + sd0;
      kpre[0][0] = ((const float4*)kb)[0];          kpre[0][1] = ((const float4*)kb)[1];
      kpre[1][0] = ((const float4*)(kb + 4096))[0]; kpre[1][1] = ((const float4*)(kb + 4096))[1];
      const float* vb = vp + base + (long)(kn + skr) * 64 + sd0;
      vpre[0][0] = ((const float4*)vb)[0];          vpre[0][1] = ((const float4*)vb)[1];
      vpre[1][0] = ((const float4*)(vb + 4096))[0]; vpre[1][1] = ((const float4*)(vb + 4096))[1];
    }

    const short* kb_ = kL[cur];
    const short* vb_ = vT[cur];

#pragma unroll
    for (int sub = 0; sub < 2; ++sub) {
      const int k0 = ph * PH + sub * 64;
      if (causal && k0 >= qw0 + 32) continue;   // subtile fully masked for this wave

      // ---- S^T = K * Q^T : C[row=key][col=q], log2 domain ----
      floatx4 sacc[4][2];
#pragma unroll
      for (int mt = 0; mt < 4; ++mt)
#pragma unroll
        for (int nt = 0; nt < 2; ++nt)
          sacc[mt][nt] = (floatx4){0.f, 0.f, 0.f, 0.f};
#pragma unroll
      for (int ks = 0; ks < 2; ++ks)
#pragma unroll
        for (int mt = 0; mt < 4; ++mt) {
          bf16x8 kfrag = *(const bf16x8*)(&kb_[(sub*64 + mt*16 + l16) * KSTR + ks*32 + lg*8]);
#pragma unroll
          for (int nt = 0; nt < 2; ++nt)
            sacc[mt][nt] = __builtin_amdgcn_mfma_f32_16x16x32_bf16(kfrag, qfrag[nt][ks], sacc[mt][nt], 0, 0, 0);
        }

      // ---- mask + per-lane max (no cross-lane yet) ----
      const bool needmask = causal && (k0 + BN - 1 > qw0);
      float pmax[2] = {-__builtin_inff(), -__builtin_inff()};
#pragma unroll
      for (int mt = 0; mt < 4; ++mt)
#pragma unroll
        for (int nt = 0; nt < 2; ++nt)
#pragma unroll
          for (int r = 0; r < 4; ++r) {
            float v = sacc[mt][nt][r];
            if (needmask) {
              int key = k0  + mt*16 + lg*4 + r;
              int q   = qw0 + nt*16 + l16;
              if (q < key) v = -__builtin_inff();
            }
            sacc[mt][nt][r] = v;
            pmax[nt] = fmaxf(pmax[nt], v);
          }

      // ---- defer-max: rescale only if per-lane max grew past THR ----
      // (NaN from -inf - -inf on the first subtile makes the test false -> rescale path)
      const bool nore = __all(fmaxf(pmax[0] - m_run[0], pmax[1] - m_run[1]) <= RESCALE_THR);
      if (!nore) {
#pragma unroll
        for (int nt = 0; nt < 2; ++nt) {
          pmax[nt] = fmaxf(pmax[nt], __shfl_xor(pmax[nt], 16));
          pmax[nt] = fmaxf(pmax[nt], __shfl_xor(pmax[nt], 32));
        }
        float alpha[2];
#pragma unroll
        for (int nt = 0; nt < 2; ++nt) {
          float mnew = fmaxf(m_run[nt], pmax[nt]);
          alpha[nt]  = __builtin_amdgcn_exp2f(m_run[nt] - mnew);  // first subtile: exp2(-inf)=0
          m_run[nt]  = mnew;
          l_run[nt] *= alpha[nt];
        }
        // rescale O accumulator (alpha from q=l16 layout to q=lg*4+r layout)
#pragma unroll
        for (int mo = 0; mo < 2; ++mo)
#pragma unroll
          for (int r = 0; r < 4; ++r) {
            float al = __shfl(alpha[mo], lg*4 + r);
#pragma unroll
            for (int nd = 0; nd < 4; ++nd)
              oacc[mo][nd][r] *= al;
          }
      }

      // ---- exp (vs possibly-stale m_run, bounded by 2^THR) + pack P ----
      bf16x8 pfrag[2][2];
      float rsum[2] = {0.f, 0.f};
#pragma unroll
      for (int nt = 0; nt < 2; ++nt)
#pragma unroll
        for (int ks = 0; ks < 2; ++ks) {
          union { short s[8]; bf16x8 v; } pk;
#pragma unroll
          for (int r = 0; r < 4; ++r) {
            float e0 = __builtin_amdgcn_exp2f(sacc[ks][nt][r]     - m_run[nt]);
            float e1 = __builtin_amdgcn_exp2f(sacc[ks + 2][nt][r] - m_run[nt]);
            rsum[nt] += e0 + e1;
            pk.s[r]     = f2bf(e0);
            pk.s[4 + r] = f2bf(e1);
          }
          pfrag[nt][ks] = pk.v;
        }
#pragma unroll
      for (int nt = 0; nt < 2; ++nt)
        l_run[nt] += rsum[nt];   // per-lane partial; reduced in epilogue

      // ---- O += P * V (V^T columns key-permuted to match pfrag) ----
#pragma unroll
      for (int ks = 0; ks < 2; ++ks) {
        bf16x8 vfrag[4];
#pragma unroll
        for (int nd = 0; nd < 4; ++nd) {
          int colr = (ks*32 + lg*8 + nd*16) & 63;   // un-rotate d-dependent rotation
          vfrag[nd] = *(const bf16x8*)(&vb_[(nd*16 + l16) * VSTR + sub*64 + colr]);
        }
#pragma unroll
        for (int mo = 0; mo < 2; ++mo)
#pragma unroll
          for (int nd = 0; nd < 4; ++nd)
            oacc[mo][nd] = __builtin_amdgcn_mfma_f32_16x16x32_bf16(pfrag[mo][ks], vfrag[nd], oacc[mo][nd], 0, 0, 0);
      }
    }

    cur ^= 1;   // no second barrier: ph+1's barrier guards buf reuse at ph+2
  }

  // ---- epilogue: reduce partial l across lg copies, then O / l ----
#pragma unroll
  for (int nt = 0; nt < 2; ++nt) {
    l_run[nt] += __shfl_xor(l_run[nt], 16);
    l_run[nt] += __shfl_xor(l_run[nt], 32);
  }
#pragma unroll
  for (int mo = 0; mo < 2; ++mo)
#pragma unroll
    for (int r = 0; r < 4; ++r) {
      float lv  = __shfl(l_run[mo], lg*4 + r);
      float inv = __builtin_amdgcn_rcpf(lv);
      int qrow  = qw0 + mo*16 + lg*4 + r;
#pragma unroll
      for (int nd = 0; nd < 4; ++nd)
        op[base + (long)qrow * 64 + nd*16 + l16] = oacc[mo][nd][r] * inv;
    }
}

extern "C" void kernel_launch(void* const* d_in, const int* in_sizes, int n_in,
                              void* d_out, int out_size, void* d_ws, size_t ws_size,
                              hipStream_t stream) {
  const float* q = (const float*)d_in[0];
  const float* k = (const float*)d_in[1];
  const float* v = (const float*)d_in[2];
  const int*  cm = (const int*)d_in[3];
  float* o = (float*)d_out;
  dim3 grid(S_LEN / BM, NBH);
  mea_fwd<<<grid, dim3(512, 1, 1), 0, stream>>>(q, k, v, cm, o);
}